// Round 2
// baseline (5769.318 us; speedup 1.0000x reference)
//
#include <hip/hip_runtime.h>

#define N_NODES 50000
#define E_EDGES 800000
#define F_IN 512
#define HID 128
#define N_LAYERS 4
#define C_OUT 40

// ---------------- degree / norm ----------------
__global__ void deg_init(float* deg) {
    int i = blockIdx.x * 256 + threadIdx.x;
    if (i < N_NODES) deg[i] = 1.0f;  // self-loop
}

__global__ void deg_count(const int* __restrict__ ei, float* deg) {
    int e = blockIdx.x * 256 + threadIdx.x;
    if (e < E_EDGES) {
        unsigned d = (unsigned)ei[E_EDGES + e];
        if (d < N_NODES) atomicAdd(&deg[d], 1.0f);
    }
}

__global__ void dinv_k(float* deg) {
    int i = blockIdx.x * 256 + threadIdx.x;
    if (i < N_NODES) deg[i] = rsqrtf(deg[i]);
}

// ---------------- input GEMM: h = relu(x @ W_in + b_in), x0 = h ----------------
// M=50000, K=512, N=128. BM=64, KT=64. 256 threads: 8 rows x 4 cols each.
__launch_bounds__(256)
__global__ void gemm_in(const float* __restrict__ x, const float* __restrict__ Wi,
                        const float* __restrict__ bi,
                        float* __restrict__ h, float* __restrict__ x0) {
    __shared__ float As[64][64];    // 16 KB
    __shared__ float Bs[64][128];   // 32 KB
    const int t = threadIdx.x;
    const int row0 = blockIdx.x * 64;
    const int cg = t & 31;          // col group: cols cg*4 .. cg*4+3
    const int rg = t >> 5;          // row group: rows rg*8 .. rg*8+7

    float acc[8][4] = {};

    for (int k0 = 0; k0 < F_IN; k0 += 64) {
        // load A tile 64x64 (1024 float4, 4 per thread, 16 f4 per row)
        #pragma unroll
        for (int i = 0; i < 4; i++) {
            int q = t + i * 256;
            int r = q >> 4, c4 = q & 15;
            int grow = row0 + r;
            float4 v = make_float4(0.f, 0.f, 0.f, 0.f);
            if (grow < N_NODES) v = *(const float4*)&x[(size_t)grow * F_IN + k0 + c4 * 4];
            *(float4*)&As[r][c4 * 4] = v;
        }
        // load B tile 64x128 (2048 float4, 8 per thread, 32 f4 per row)
        #pragma unroll
        for (int i = 0; i < 8; i++) {
            int q = t + i * 256;
            int r = q >> 5, c4 = q & 31;
            *(float4*)&Bs[r][c4 * 4] = *(const float4*)&Wi[(size_t)(k0 + r) * HID + c4 * 4];
        }
        __syncthreads();
        #pragma unroll 8
        for (int k = 0; k < 64; k++) {
            float4 b = *(const float4*)&Bs[k][cg * 4];
            #pragma unroll
            for (int i = 0; i < 8; i++) {
                float a = As[rg * 8 + i][k];
                acc[i][0] = fmaf(a, b.x, acc[i][0]);
                acc[i][1] = fmaf(a, b.y, acc[i][1]);
                acc[i][2] = fmaf(a, b.z, acc[i][2]);
                acc[i][3] = fmaf(a, b.w, acc[i][3]);
            }
        }
        __syncthreads();
    }

    float4 bias = *(const float4*)&bi[cg * 4];
    #pragma unroll
    for (int i = 0; i < 8; i++) {
        int grow = row0 + rg * 8 + i;
        if (grow < N_NODES) {
            float4 v;
            v.x = fmaxf(acc[i][0] + bias.x, 0.f);
            v.y = fmaxf(acc[i][1] + bias.y, 0.f);
            v.z = fmaxf(acc[i][2] + bias.z, 0.f);
            v.w = fmaxf(acc[i][3] + bias.w, 0.f);
            *(float4*)&h[(size_t)grow * HID + cg * 4] = v;
            *(float4*)&x0[(size_t)grow * HID + cg * 4] = v;
        }
    }
}

// ---------------- agg init: agg[i,:] = dinv[i]^2 * h[i,:] (self-loop message) ----------------
__global__ void agg_init(const float* __restrict__ dinv, const float* __restrict__ h,
                         float* __restrict__ agg) {
    int idx = blockIdx.x * 256 + threadIdx.x;   // one float4 per thread
    if (idx < N_NODES * (HID / 4)) {
        int node = idx >> 5;
        float w = dinv[node];
        w = w * w;
        float4 v = *(const float4*)&h[(size_t)idx * 4];
        v.x *= w; v.y *= w; v.z *= w; v.w *= w;
        *(float4*)&agg[(size_t)idx * 4] = v;
    }
}

// ---------------- edge scatter: agg[dst,:] += dinv[src]*dinv[dst] * h[src,:] ----------------
// 32 threads per edge, each handles a float4 of the 128-wide feature row.
__global__ void edge_scatter(const int* __restrict__ ei, const float* __restrict__ dinv,
                             const float* __restrict__ h, float* __restrict__ agg) {
    int gi = blockIdx.x * 256 + threadIdx.x;
    int e = gi >> 5;
    int j4 = gi & 31;
    if (e < E_EDGES) {
        unsigned s = (unsigned)ei[e];
        unsigned d = (unsigned)ei[E_EDGES + e];
        if (s < N_NODES && d < N_NODES) {
            float w = dinv[s] * dinv[d];
            float4 v = *(const float4*)&h[(size_t)s * HID + j4 * 4];
            float* ap = &agg[(size_t)d * HID + j4 * 4];
            atomicAdd(ap + 0, w * v.x);
            atomicAdd(ap + 1, w * v.y);
            atomicAdd(ap + 2, w * v.z);
            atomicAdd(ap + 3, w * v.w);
        }
    }
}

// ---------------- layer GEMM (in place): agg <- SReLU((0.8*agg + 0.1*h + 0.1*x0) @ W) ----------------
// M=50000, K=128, N=128. BM=64. Each block reads exactly the rows it writes (in-place safe).
__launch_bounds__(256)
__global__ void gemm_layer(const float* __restrict__ Wl, const float* __restrict__ sb,
                           const float* __restrict__ h, const float* __restrict__ x0,
                           float* __restrict__ agg) {
    __shared__ float As[64][128];   // 32 KB (combined A)
    __shared__ float Bs[64][128];   // 32 KB (W chunk)
    const int t = threadIdx.x;
    const int row0 = blockIdx.x * 64;
    const int cg = t & 31;
    const int rg = t >> 5;

    // load + combine A tile (full K=128): 2048 float4, 8 per thread
    #pragma unroll
    for (int i = 0; i < 8; i++) {
        int q = t + i * 256;
        int r = q >> 5, c4 = q & 31;
        int grow = row0 + r;
        float4 v = make_float4(0.f, 0.f, 0.f, 0.f);
        if (grow < N_NODES) {
            size_t off = (size_t)grow * HID + c4 * 4;
            float4 a4 = *(const float4*)&agg[off];
            float4 h4 = *(const float4*)&h[off];
            float4 x4 = *(const float4*)&x0[off];
            v.x = 0.8f * a4.x + 0.1f * h4.x + 0.1f * x4.x;
            v.y = 0.8f * a4.y + 0.1f * h4.y + 0.1f * x4.y;
            v.z = 0.8f * a4.z + 0.1f * h4.z + 0.1f * x4.z;
            v.w = 0.8f * a4.w + 0.1f * h4.w + 0.1f * x4.w;
        }
        *(float4*)&As[r][c4 * 4] = v;
    }

    float acc[8][4] = {};
    for (int k0 = 0; k0 < HID; k0 += 64) {
        #pragma unroll
        for (int i = 0; i < 8; i++) {
            int q = t + i * 256;
            int r = q >> 5, c4 = q & 31;
            *(float4*)&Bs[r][c4 * 4] = *(const float4*)&Wl[(size_t)(k0 + r) * HID + c4 * 4];
        }
        __syncthreads();
        #pragma unroll 8
        for (int k = 0; k < 64; k++) {
            float4 b = *(const float4*)&Bs[k][cg * 4];
            #pragma unroll
            for (int i = 0; i < 8; i++) {
                float a = As[rg * 8 + i][k0 + k];
                acc[i][0] = fmaf(a, b.x, acc[i][0]);
                acc[i][1] = fmaf(a, b.y, acc[i][1]);
                acc[i][2] = fmaf(a, b.z, acc[i][2]);
                acc[i][3] = fmaf(a, b.w, acc[i][3]);
            }
        }
        __syncthreads();
    }

    // SReLU(v) = relu(v - sb) + sb = max(v, sb)
    float4 s4 = *(const float4*)&sb[cg * 4];
    #pragma unroll
    for (int i = 0; i < 8; i++) {
        int grow = row0 + rg * 8 + i;
        if (grow < N_NODES) {
            float4 v;
            v.x = fmaxf(acc[i][0], s4.x);
            v.y = fmaxf(acc[i][1], s4.y);
            v.z = fmaxf(acc[i][2], s4.z);
            v.w = fmaxf(acc[i][3], s4.w);
            *(float4*)&agg[(size_t)grow * HID + cg * 4] = v;
        }
    }
}

// ---------------- output GEMM: out = h @ W_out + b_out ----------------
// M=50000, K=128, N=40. BM=64. 256 threads: thread t -> row t/4, cols (t%4)+4i, i<10.
__launch_bounds__(256)
__global__ void gemm_out(const float* __restrict__ h, const float* __restrict__ Wo,
                         const float* __restrict__ bo, float* __restrict__ out) {
    __shared__ float As[64][129];    // padded: stride-128 rows would alias banks
    __shared__ float Ws[128][40];
    const int t = threadIdx.x;
    const int row0 = blockIdx.x * 64;

    #pragma unroll
    for (int i = 0; i < 8; i++) {
        int q = t + i * 256;
        int r = q >> 5, c4 = q & 31;
        int grow = row0 + r;
        float4 v = make_float4(0.f, 0.f, 0.f, 0.f);
        if (grow < N_NODES) v = *(const float4*)&h[(size_t)grow * HID + c4 * 4];
        As[r][c4 * 4 + 0] = v.x;
        As[r][c4 * 4 + 1] = v.y;
        As[r][c4 * 4 + 2] = v.z;
        As[r][c4 * 4 + 3] = v.w;
    }
    #pragma unroll
    for (int i = 0; i < 20; i++) {
        int idx = t + i * 256;
        Ws[idx / 40][idx % 40] = Wo[idx];
    }
    __syncthreads();

    const int r = t >> 2;
    const int c0 = t & 3;
    float acc[10] = {};
    #pragma unroll 4
    for (int k = 0; k < HID; k++) {
        float a = As[r][k];
        #pragma unroll
        for (int i = 0; i < 10; i++) {
            acc[i] = fmaf(a, Ws[k][c0 + 4 * i], acc[i]);
        }
    }
    int grow = row0 + r;
    if (grow < N_NODES) {
        #pragma unroll
        for (int i = 0; i < 10; i++) {
            out[(size_t)grow * C_OUT + c0 + 4 * i] = acc[i] + bo[c0 + 4 * i];
        }
    }
}

// ---------------- launch ----------------
extern "C" void kernel_launch(void* const* d_in, const int* in_sizes, int n_in,
                              void* d_out, int out_size, void* d_ws, size_t ws_size,
                              hipStream_t stream) {
    const float* x   = (const float*)d_in[0];
    const int*   ei  = (const int*)d_in[1];    // harness delivers integer inputs as int32
    const float* Wi  = (const float*)d_in[2];
    const float* bi  = (const float*)d_in[3];
    const float* Wls = (const float*)d_in[4];
    const float* sbs = (const float*)d_in[5];
    const float* Wo  = (const float*)d_in[6];
    const float* bo  = (const float*)d_in[7];
    float* out = (float*)d_out;

    float* dinv = (float*)d_ws;                 // 50176 floats (padded for alignment)
    float* x0   = dinv + 50176;                 // 6.4M
    float* hA   = x0   + (size_t)N_NODES * HID; // 6.4M
    float* hB   = hA   + (size_t)N_NODES * HID; // 6.4M

    const int nodeBlocks = (N_NODES + 255) / 256;
    const int gemmBlocks = (N_NODES + 63) / 64;

    deg_init<<<nodeBlocks, 256, 0, stream>>>(dinv);
    deg_count<<<(E_EDGES + 255) / 256, 256, 0, stream>>>(ei, dinv);
    dinv_k<<<nodeBlocks, 256, 0, stream>>>(dinv);

    gemm_in<<<gemmBlocks, 256, 0, stream>>>(x, Wi, bi, hA, x0);

    float* h   = hA;
    float* agg = hB;
    for (int l = 0; l < N_LAYERS; l++) {
        agg_init<<<(N_NODES * (HID / 4) + 255) / 256, 256, 0, stream>>>(dinv, h, agg);
        edge_scatter<<<(E_EDGES * 32) / 256, 256, 0, stream>>>(ei, dinv, h, agg);
        gemm_layer<<<gemmBlocks, 256, 0, stream>>>(Wls + (size_t)l * HID * HID,
                                                   sbs + (size_t)l * HID,
                                                   h, x0, agg);
        float* tmp = h; h = agg; agg = tmp;  // result now lives in old agg buffer
    }

    gemm_out<<<gemmBlocks, 256, 0, stream>>>(h, Wo, bo, out);
}

// Round 3
// 863.574 us; speedup vs baseline: 6.6807x; 6.6807x over previous
//
#include <hip/hip_runtime.h>

#define N_NODES 50000
#define E_EDGES 800000
#define F_IN 512
#define HID 128
#define N_LAYERS 4
#define C_OUT 40

// ---------------- degree / norm ----------------
__global__ void zero_int(int* p, int n) {
    int i = blockIdx.x * 256 + threadIdx.x;
    if (i < n) p[i] = 0;
}

__global__ void indeg_count(const int* __restrict__ ei, int* __restrict__ indeg) {
    int e = blockIdx.x * 256 + threadIdx.x;
    if (e < E_EDGES) {
        unsigned d = (unsigned)ei[E_EDGES + e];
        if (d < N_NODES) atomicAdd(&indeg[d], 1);
    }
}

__global__ void dinv_k(const int* __restrict__ indeg, float* __restrict__ dinv) {
    int i = blockIdx.x * 256 + threadIdx.x;
    if (i < N_NODES) dinv[i] = rsqrtf(1.0f + (float)indeg[i]);  // +1 self-loop
}

// ---------------- single-block exclusive scan over indeg -> rowptr, cursor ----------------
__launch_bounds__(1024)
__global__ void scan_k(const int* __restrict__ indeg, int* __restrict__ rowptr,
                       int* __restrict__ cursor) {
    __shared__ int sums[1024];
    const int t = threadIdx.x;
    const int CH = 49;                       // 1024*49 = 50176 >= 50000
    const int base = t * CH;
    int local = 0;
    for (int i = 0; i < CH; i++) {
        int idx = base + i;
        if (idx < N_NODES) local += indeg[idx];
    }
    sums[t] = local;
    __syncthreads();
    // Hillis-Steele inclusive scan
    for (int off = 1; off < 1024; off <<= 1) {
        int v = sums[t];
        int add = (t >= off) ? sums[t - off] : 0;
        __syncthreads();
        sums[t] = v + add;
        __syncthreads();
    }
    int run = (t == 0) ? 0 : sums[t - 1];
    for (int i = 0; i < CH; i++) {
        int idx = base + i;
        if (idx < N_NODES) {
            rowptr[idx] = run;
            cursor[idx] = run;
            run += indeg[idx];
        }
    }
    if (t == 1023) rowptr[N_NODES] = sums[1023];
}

// ---------------- CSR fill: bucket edges by dst ----------------
__global__ void csr_fill(const int* __restrict__ ei, int* __restrict__ cursor,
                         int* __restrict__ csr_src) {
    int e = blockIdx.x * 256 + threadIdx.x;
    if (e < E_EDGES) {
        unsigned s = (unsigned)ei[e];
        unsigned d = (unsigned)ei[E_EDGES + e];
        if (s < N_NODES && d < N_NODES) {
            int pos = atomicAdd(&cursor[d], 1);
            csr_src[pos] = (int)s;
        }
    }
}

// ---------------- input GEMM: h = relu(x @ W_in + b_in), x0 = h ----------------
__launch_bounds__(256)
__global__ void gemm_in(const float* __restrict__ x, const float* __restrict__ Wi,
                        const float* __restrict__ bi,
                        float* __restrict__ h, float* __restrict__ x0) {
    __shared__ float As[64][64];
    __shared__ float Bs[64][128];
    const int t = threadIdx.x;
    const int row0 = blockIdx.x * 64;
    const int cg = t & 31;
    const int rg = t >> 5;

    float acc[8][4] = {};

    for (int k0 = 0; k0 < F_IN; k0 += 64) {
        #pragma unroll
        for (int i = 0; i < 4; i++) {
            int q = t + i * 256;
            int r = q >> 4, c4 = q & 15;
            int grow = row0 + r;
            float4 v = make_float4(0.f, 0.f, 0.f, 0.f);
            if (grow < N_NODES) v = *(const float4*)&x[(size_t)grow * F_IN + k0 + c4 * 4];
            *(float4*)&As[r][c4 * 4] = v;
        }
        #pragma unroll
        for (int i = 0; i < 8; i++) {
            int q = t + i * 256;
            int r = q >> 5, c4 = q & 31;
            *(float4*)&Bs[r][c4 * 4] = *(const float4*)&Wi[(size_t)(k0 + r) * HID + c4 * 4];
        }
        __syncthreads();
        #pragma unroll 8
        for (int k = 0; k < 64; k++) {
            float4 b = *(const float4*)&Bs[k][cg * 4];
            #pragma unroll
            for (int i = 0; i < 8; i++) {
                float a = As[rg * 8 + i][k];
                acc[i][0] = fmaf(a, b.x, acc[i][0]);
                acc[i][1] = fmaf(a, b.y, acc[i][1]);
                acc[i][2] = fmaf(a, b.z, acc[i][2]);
                acc[i][3] = fmaf(a, b.w, acc[i][3]);
            }
        }
        __syncthreads();
    }

    float4 bias = *(const float4*)&bi[cg * 4];
    #pragma unroll
    for (int i = 0; i < 8; i++) {
        int grow = row0 + rg * 8 + i;
        if (grow < N_NODES) {
            float4 v;
            v.x = fmaxf(acc[i][0] + bias.x, 0.f);
            v.y = fmaxf(acc[i][1] + bias.y, 0.f);
            v.z = fmaxf(acc[i][2] + bias.z, 0.f);
            v.w = fmaxf(acc[i][3] + bias.w, 0.f);
            *(float4*)&h[(size_t)grow * HID + cg * 4] = v;
            *(float4*)&x0[(size_t)grow * HID + cg * 4] = v;
        }
    }
}

// ---------------- aggregate (CSR gather) + residual combine ----------------
// One wave per dst node; lane owns float2 of the 128-wide row.
// comb = 0.8*(dinv_d*(sum_e dinv[s]*h[s]) + dinv_d^2*h[d]) + 0.1*h[d] + 0.1*x0[d]
__launch_bounds__(256)
__global__ void aggregate(const int* __restrict__ rowptr, const int* __restrict__ csr_src,
                          const float* __restrict__ dinv,
                          const float* __restrict__ h, const float* __restrict__ x0,
                          float* __restrict__ comb) {
    const int wid = threadIdx.x >> 6;
    const int lane = threadIdx.x & 63;
    const int node = blockIdx.x * 4 + wid;
    if (node >= N_NODES) return;

    const float2* h2 = (const float2*)h;
    const float2* x2 = (const float2*)x0;
    const float dd = dinv[node];
    const int beg = rowptr[node];
    const int end = rowptr[node + 1];

    float2 sum = make_float2(0.f, 0.f);
    for (int e = beg; e < end; e++) {
        int s = csr_src[e];
        float ws = dinv[s];
        float2 v = h2[(size_t)s * 64 + lane];
        sum.x = fmaf(ws, v.x, sum.x);
        sum.y = fmaf(ws, v.y, sum.y);
    }

    float2 hv = h2[(size_t)node * 64 + lane];
    float2 xv = x2[(size_t)node * 64 + lane];
    const float a = 0.8f * dd;
    float2 o;
    o.x = a * fmaf(dd, hv.x, sum.x) + 0.1f * hv.x + 0.1f * xv.x;
    o.y = a * fmaf(dd, hv.y, sum.y) + 0.1f * hv.y + 0.1f * xv.y;
    ((float2*)comb)[(size_t)node * 64 + lane] = o;
}

// ---------------- layer GEMM (in place): comb <- SReLU(comb @ W) ----------------
__launch_bounds__(256)
__global__ void gemm_layer(const float* __restrict__ Wl, const float* __restrict__ sb,
                           float* __restrict__ comb) {
    __shared__ float As[64][128];
    __shared__ float Bs[64][128];
    const int t = threadIdx.x;
    const int row0 = blockIdx.x * 64;
    const int cg = t & 31;
    const int rg = t >> 5;

    #pragma unroll
    for (int i = 0; i < 8; i++) {
        int q = t + i * 256;
        int r = q >> 5, c4 = q & 31;
        int grow = row0 + r;
        float4 v = make_float4(0.f, 0.f, 0.f, 0.f);
        if (grow < N_NODES) v = *(const float4*)&comb[(size_t)grow * HID + c4 * 4];
        *(float4*)&As[r][c4 * 4] = v;
    }

    float acc[8][4] = {};
    for (int k0 = 0; k0 < HID; k0 += 64) {
        #pragma unroll
        for (int i = 0; i < 8; i++) {
            int q = t + i * 256;
            int r = q >> 5, c4 = q & 31;
            *(float4*)&Bs[r][c4 * 4] = *(const float4*)&Wl[(size_t)(k0 + r) * HID + c4 * 4];
        }
        __syncthreads();
        #pragma unroll 8
        for (int k = 0; k < 64; k++) {
            float4 b = *(const float4*)&Bs[k][cg * 4];
            #pragma unroll
            for (int i = 0; i < 8; i++) {
                float a = As[rg * 8 + i][k0 + k];
                acc[i][0] = fmaf(a, b.x, acc[i][0]);
                acc[i][1] = fmaf(a, b.y, acc[i][1]);
                acc[i][2] = fmaf(a, b.z, acc[i][2]);
                acc[i][3] = fmaf(a, b.w, acc[i][3]);
            }
        }
        __syncthreads();
    }

    float4 s4 = *(const float4*)&sb[cg * 4];
    #pragma unroll
    for (int i = 0; i < 8; i++) {
        int grow = row0 + rg * 8 + i;
        if (grow < N_NODES) {
            float4 v;
            v.x = fmaxf(acc[i][0], s4.x);
            v.y = fmaxf(acc[i][1], s4.y);
            v.z = fmaxf(acc[i][2], s4.z);
            v.w = fmaxf(acc[i][3], s4.w);
            *(float4*)&comb[(size_t)grow * HID + cg * 4] = v;
        }
    }
}

// ---------------- output GEMM: out = h @ W_out + b_out ----------------
__launch_bounds__(256)
__global__ void gemm_out(const float* __restrict__ h, const float* __restrict__ Wo,
                         const float* __restrict__ bo, float* __restrict__ out) {
    __shared__ float As[64][129];
    __shared__ float Ws[128][40];
    const int t = threadIdx.x;
    const int row0 = blockIdx.x * 64;

    #pragma unroll
    for (int i = 0; i < 8; i++) {
        int q = t + i * 256;
        int r = q >> 5, c4 = q & 31;
        int grow = row0 + r;
        float4 v = make_float4(0.f, 0.f, 0.f, 0.f);
        if (grow < N_NODES) v = *(const float4*)&h[(size_t)grow * HID + c4 * 4];
        As[r][c4 * 4 + 0] = v.x;
        As[r][c4 * 4 + 1] = v.y;
        As[r][c4 * 4 + 2] = v.z;
        As[r][c4 * 4 + 3] = v.w;
    }
    #pragma unroll
    for (int i = 0; i < 20; i++) {
        int idx = t + i * 256;
        Ws[idx / 40][idx % 40] = Wo[idx];
    }
    __syncthreads();

    const int r = t >> 2;
    const int c0 = t & 3;
    float acc[10] = {};
    #pragma unroll 4
    for (int k = 0; k < HID; k++) {
        float a = As[r][k];
        #pragma unroll
        for (int i = 0; i < 10; i++) {
            acc[i] = fmaf(a, Ws[k][c0 + 4 * i], acc[i]);
        }
    }
    int grow = row0 + r;
    if (grow < N_NODES) {
        #pragma unroll
        for (int i = 0; i < 10; i++) {
            out[(size_t)grow * C_OUT + c0 + 4 * i] = acc[i] + bo[c0 + 4 * i];
        }
    }
}

// ---------------- launch ----------------
extern "C" void kernel_launch(void* const* d_in, const int* in_sizes, int n_in,
                              void* d_out, int out_size, void* d_ws, size_t ws_size,
                              hipStream_t stream) {
    const float* x   = (const float*)d_in[0];
    const int*   ei  = (const int*)d_in[1];    // int32 on device
    const float* Wi  = (const float*)d_in[2];
    const float* bi  = (const float*)d_in[3];
    const float* Wls = (const float*)d_in[4];
    const float* sbs = (const float*)d_in[5];
    const float* Wo  = (const float*)d_in[6];
    const float* bo  = (const float*)d_in[7];
    float* out = (float*)d_out;

    // workspace layout (all 16B-aligned)
    float* dinv    = (float*)d_ws;                         // 50176 f
    int*   indeg   = (int*)(dinv + 50176);                 // 50176 i
    int*   rowptr  = indeg + 50176;                        // 50304 i (need 50001)
    int*   cursor  = rowptr + 50304;                       // 50176 i
    int*   csr_src = cursor + 50176;                       // 800000 i
    float* x0      = (float*)(csr_src + 800000);           // 6.4M f
    float* hA      = x0 + (size_t)N_NODES * HID;           // 6.4M f
    float* hB      = hA + (size_t)N_NODES * HID;           // 6.4M f

    const int nodeBlocks = (N_NODES + 255) / 256;
    const int edgeBlocks = (E_EDGES + 255) / 256;
    const int gemmBlocks = (N_NODES + 63) / 64;
    const int aggBlocks  = (N_NODES + 3) / 4;

    zero_int<<<nodeBlocks, 256, 0, stream>>>(indeg, N_NODES);
    indeg_count<<<edgeBlocks, 256, 0, stream>>>(ei, indeg);
    dinv_k<<<nodeBlocks, 256, 0, stream>>>(indeg, dinv);
    scan_k<<<1, 1024, 0, stream>>>(indeg, rowptr, cursor);
    csr_fill<<<edgeBlocks, 256, 0, stream>>>(ei, cursor, csr_src);

    gemm_in<<<gemmBlocks, 256, 0, stream>>>(x, Wi, bi, hA, x0);

    float* h    = hA;
    float* next = hB;
    for (int l = 0; l < N_LAYERS; l++) {
        aggregate<<<aggBlocks, 256, 0, stream>>>(rowptr, csr_src, dinv, h, x0, next);
        gemm_layer<<<gemmBlocks, 256, 0, stream>>>(Wls + (size_t)l * HID * HID,
                                                   sbs + (size_t)l * HID, next);
        float* tmp = h; h = next; next = tmp;
    }

    gemm_out<<<gemmBlocks, 256, 0, stream>>>(h, Wo, bo, out);
}

// Round 4
// 787.889 us; speedup vs baseline: 7.3225x; 1.0961x over previous
//
#include <hip/hip_runtime.h>

#define N_NODES 50000
#define E_EDGES 800000
#define F_IN 512
#define HID 128
#define N_LAYERS 4
#define C_OUT 40

typedef __attribute__((ext_vector_type(8))) short bf16x8;
typedef __attribute__((ext_vector_type(4))) float f32x4;

// split fp32 into bf16 hi (RNE) + bf16 lo (residual); a ~= hi + lo with ~2^-17 rel error
__device__ __forceinline__ void split2(float a, unsigned short& hi, unsigned short& lo) {
    unsigned u = __float_as_uint(a);
    unsigned r = u + 0x7FFFu + ((u >> 16) & 1u);
    hi = (unsigned short)(r >> 16);
    float hf = __uint_as_float(((unsigned)hi) << 16);
    lo = (unsigned short)(__float_as_uint(a - hf) >> 16);
}

// ---------------- degree / norm ----------------
__global__ void zero_int(int* p, int n) {
    int i = blockIdx.x * 256 + threadIdx.x;
    if (i < n) p[i] = 0;
}

__global__ void indeg_count(const int* __restrict__ ei, int* __restrict__ indeg) {
    int e = blockIdx.x * 256 + threadIdx.x;
    if (e < E_EDGES) {
        unsigned d = (unsigned)ei[E_EDGES + e];
        if (d < N_NODES) atomicAdd(&indeg[d], 1);
    }
}

__global__ void dinv_k(const int* __restrict__ indeg, float* __restrict__ dinv) {
    int i = blockIdx.x * 256 + threadIdx.x;
    if (i < N_NODES) dinv[i] = rsqrtf(1.0f + (float)indeg[i]);
}

// ---------------- single-block exclusive scan -> rowptr, cursor ----------------
__launch_bounds__(1024)
__global__ void scan_k(const int* __restrict__ indeg, int* __restrict__ rowptr,
                       int* __restrict__ cursor) {
    __shared__ int sums[1024];
    const int t = threadIdx.x;
    const int CH = 49;
    const int base = t * CH;
    int local = 0;
    for (int i = 0; i < CH; i++) {
        int idx = base + i;
        if (idx < N_NODES) local += indeg[idx];
    }
    sums[t] = local;
    __syncthreads();
    for (int off = 1; off < 1024; off <<= 1) {
        int v = sums[t];
        int add = (t >= off) ? sums[t - off] : 0;
        __syncthreads();
        sums[t] = v + add;
        __syncthreads();
    }
    int run = (t == 0) ? 0 : sums[t - 1];
    for (int i = 0; i < CH; i++) {
        int idx = base + i;
        if (idx < N_NODES) {
            rowptr[idx] = run;
            cursor[idx] = run;
            run += indeg[idx];
        }
    }
    if (t == 1023) rowptr[N_NODES] = sums[1023];
}

// ---------------- CSR fill ----------------
__global__ void csr_fill(const int* __restrict__ ei, int* __restrict__ cursor,
                         int* __restrict__ csr_src) {
    int e = blockIdx.x * 256 + threadIdx.x;
    if (e < E_EDGES) {
        unsigned s = (unsigned)ei[e];
        unsigned d = (unsigned)ei[E_EDGES + e];
        if (s < N_NODES && d < N_NODES) {
            int pos = atomicAdd(&cursor[d], 1);
            csr_src[pos] = (int)s;
        }
    }
}

// ---------------- weight prep: W[K][N] fp32 -> Wt_hi/Wt_lo [N][K] bf16 ----------------
__global__ void wprep_in(const float* __restrict__ W, unsigned short* __restrict__ Whi,
                         unsigned short* __restrict__ Wlo) {
    int idx = blockIdx.x * 256 + threadIdx.x;
    if (idx < F_IN * HID) {
        int k = idx >> 7, n = idx & 127;
        unsigned short hi, lo;
        split2(W[idx], hi, lo);
        Whi[(size_t)n * F_IN + k] = hi;
        Wlo[(size_t)n * F_IN + k] = lo;
    }
}

__global__ void wprep_layers(const float* __restrict__ W, unsigned short* __restrict__ Whi,
                             unsigned short* __restrict__ Wlo) {
    int idx = blockIdx.x * 256 + threadIdx.x;
    if (idx < N_LAYERS * HID * HID) {
        int l = idx >> 14;
        int rem = idx & 16383;
        int k = rem >> 7, n = rem & 127;
        unsigned short hi, lo;
        split2(W[idx], hi, lo);
        Whi[(size_t)l * HID * HID + n * HID + k] = hi;
        Wlo[(size_t)l * HID * HID + n * HID + k] = lo;
    }
}

// ---------------- input GEMM (MFMA split-bf16): h = relu(x @ W_in + b), x0 = h ----------------
// BM=64, 4 waves; wave w owns rows w*16..w*16+15, all 128 cols (8 n-tiles).
__launch_bounds__(256)
__global__ void gemm_in_mfma(const float* __restrict__ x,
                             const unsigned short* __restrict__ Bth,
                             const unsigned short* __restrict__ Btl,
                             const float* __restrict__ bi,
                             float* __restrict__ h, float* __restrict__ x0) {
    __shared__ __align__(16) unsigned short Ahi[64 * 64];
    __shared__ __align__(16) unsigned short Alo[64 * 64];
    const int t = threadIdx.x;
    const int lane = t & 63;
    const int wv = t >> 6;
    const int row0 = blockIdx.x * 64;

    f32x4 acc[8] = {};

    const int fr = lane & 15;            // A row / B col within tile
    const int fk = (lane >> 4) * 8;      // k offset within K=32 step

    for (int k0 = 0; k0 < F_IN; k0 += 64) {
        // stage A 64x64 fp32 -> bf16 hi/lo, swizzled
        #pragma unroll
        for (int i = 0; i < 4; i++) {
            int q = t + i * 256;
            int r = q >> 4, c4 = q & 15;
            int grow = row0 + r;
            float4 v = make_float4(0.f, 0.f, 0.f, 0.f);
            if (grow < N_NODES) v = *(const float4*)&x[(size_t)grow * F_IN + k0 + c4 * 4];
            ushort4 uh, ul;
            split2(v.x, uh.x, ul.x); split2(v.y, uh.y, ul.y);
            split2(v.z, uh.z, ul.z); split2(v.w, uh.w, ul.w);
            int idx = (r * 64 + c4 * 4) ^ ((r & 7) << 3);   // XOR-swizzle (byte<<4)
            *(ushort4*)&Ahi[idx] = uh;
            *(ushort4*)&Alo[idx] = ul;
        }
        __syncthreads();
        #pragma unroll
        for (int kk = 0; kk < 2; kk++) {
            int arow = wv * 16 + fr;
            int aidx = (arow * 64 + kk * 32 + fk) ^ ((arow & 7) << 3);
            bf16x8 ah = *(bf16x8*)&Ahi[aidx];
            bf16x8 al = *(bf16x8*)&Alo[aidx];
            #pragma unroll
            for (int nt = 0; nt < 8; nt++) {
                size_t boff = (size_t)(nt * 16 + fr) * F_IN + k0 + kk * 32 + fk;
                bf16x8 bh = *(const bf16x8*)&Bth[boff];
                bf16x8 bl = *(const bf16x8*)&Btl[boff];
                acc[nt] = __builtin_amdgcn_mfma_f32_16x16x32_bf16(al, bh, acc[nt], 0, 0, 0);
                acc[nt] = __builtin_amdgcn_mfma_f32_16x16x32_bf16(ah, bl, acc[nt], 0, 0, 0);
                acc[nt] = __builtin_amdgcn_mfma_f32_16x16x32_bf16(ah, bh, acc[nt], 0, 0, 0);
            }
        }
        __syncthreads();
    }

    const int drow0 = wv * 16 + (lane >> 4) * 4;   // C/D: col=lane&15, row=(lane>>4)*4+j
    const int dcol = lane & 15;
    #pragma unroll
    for (int nt = 0; nt < 8; nt++) {
        int gcol = nt * 16 + dcol;
        float b = bi[gcol];
        #pragma unroll
        for (int j = 0; j < 4; j++) {
            int grow = row0 + drow0 + j;
            if (grow < N_NODES) {
                float v = fmaxf(acc[nt][j] + b, 0.f);
                h[(size_t)grow * HID + gcol] = v;
                x0[(size_t)grow * HID + gcol] = v;
            }
        }
    }
}

// ---------------- aggregate (CSR gather) + residual combine ----------------
__launch_bounds__(256)
__global__ void aggregate(const int* __restrict__ rowptr, const int* __restrict__ csr_src,
                          const float* __restrict__ dinv,
                          const float* __restrict__ h, const float* __restrict__ x0,
                          float* __restrict__ comb) {
    const int wid = threadIdx.x >> 6;
    const int lane = threadIdx.x & 63;
    const int node = blockIdx.x * 4 + wid;
    if (node >= N_NODES) return;

    const float2* h2 = (const float2*)h;
    const float2* x2 = (const float2*)x0;
    const float dd = dinv[node];
    const int beg = rowptr[node];
    const int end = rowptr[node + 1];

    float2 s0 = make_float2(0.f, 0.f);
    float2 s1 = make_float2(0.f, 0.f);
    int e = beg;
    for (; e + 2 <= end; e += 2) {
        int sa = csr_src[e];
        int sb = csr_src[e + 1];
        float wa = dinv[sa];
        float wb = dinv[sb];
        float2 va = h2[(size_t)sa * 64 + lane];
        float2 vb = h2[(size_t)sb * 64 + lane];
        s0.x = fmaf(wa, va.x, s0.x); s0.y = fmaf(wa, va.y, s0.y);
        s1.x = fmaf(wb, vb.x, s1.x); s1.y = fmaf(wb, vb.y, s1.y);
    }
    if (e < end) {
        int sa = csr_src[e];
        float wa = dinv[sa];
        float2 va = h2[(size_t)sa * 64 + lane];
        s0.x = fmaf(wa, va.x, s0.x); s0.y = fmaf(wa, va.y, s0.y);
    }
    float2 sum = make_float2(s0.x + s1.x, s0.y + s1.y);

    float2 hv = h2[(size_t)node * 64 + lane];
    float2 xv = x2[(size_t)node * 64 + lane];
    const float a = 0.8f * dd;
    float2 o;
    o.x = a * fmaf(dd, hv.x, sum.x) + 0.1f * hv.x + 0.1f * xv.x;
    o.y = a * fmaf(dd, hv.y, sum.y) + 0.1f * hv.y + 0.1f * xv.y;
    ((float2*)comb)[(size_t)node * 64 + lane] = o;
}

// ---------------- layer GEMM (MFMA split-bf16, in place): comb <- SReLU(comb @ W) ----------------
__launch_bounds__(256)
__global__ void gemm_layer_mfma(const unsigned short* __restrict__ Bth,
                                const unsigned short* __restrict__ Btl,
                                const float* __restrict__ sb,
                                float* __restrict__ comb) {
    __shared__ __align__(16) unsigned short Ahi[64 * 128];
    __shared__ __align__(16) unsigned short Alo[64 * 128];
    const int t = threadIdx.x;
    const int lane = t & 63;
    const int wv = t >> 6;
    const int row0 = blockIdx.x * 64;

    f32x4 acc[8] = {};

    const int fr = lane & 15;
    const int fk = (lane >> 4) * 8;

    // stage A 64x128 fp32 -> bf16 hi/lo (full K), swizzled
    #pragma unroll
    for (int i = 0; i < 8; i++) {
        int q = t + i * 256;
        int r = q >> 5, c4 = q & 31;
        int grow = row0 + r;
        float4 v = make_float4(0.f, 0.f, 0.f, 0.f);
        if (grow < N_NODES) v = *(const float4*)&comb[(size_t)grow * HID + c4 * 4];
        ushort4 uh, ul;
        split2(v.x, uh.x, ul.x); split2(v.y, uh.y, ul.y);
        split2(v.z, uh.z, ul.z); split2(v.w, uh.w, ul.w);
        int idx = (r * 128 + c4 * 4) ^ ((r & 7) << 3);
        *(ushort4*)&Ahi[idx] = uh;
        *(ushort4*)&Alo[idx] = ul;
    }
    __syncthreads();

    #pragma unroll
    for (int kk = 0; kk < 4; kk++) {
        int arow = wv * 16 + fr;
        int aidx = (arow * 128 + kk * 32 + fk) ^ ((arow & 7) << 3);
        bf16x8 ah = *(bf16x8*)&Ahi[aidx];
        bf16x8 al = *(bf16x8*)&Alo[aidx];
        #pragma unroll
        for (int nt = 0; nt < 8; nt++) {
            size_t boff = (size_t)(nt * 16 + fr) * HID + kk * 32 + fk;
            bf16x8 bh = *(const bf16x8*)&Bth[boff];
            bf16x8 bl = *(const bf16x8*)&Btl[boff];
            acc[nt] = __builtin_amdgcn_mfma_f32_16x16x32_bf16(al, bh, acc[nt], 0, 0, 0);
            acc[nt] = __builtin_amdgcn_mfma_f32_16x16x32_bf16(ah, bl, acc[nt], 0, 0, 0);
            acc[nt] = __builtin_amdgcn_mfma_f32_16x16x32_bf16(ah, bh, acc[nt], 0, 0, 0);
        }
    }

    // SReLU(v) = max(v, sb). In-place safe: this block reads only its own rows (already staged).
    const int drow0 = wv * 16 + (lane >> 4) * 4;
    const int dcol = lane & 15;
    #pragma unroll
    for (int nt = 0; nt < 8; nt++) {
        int gcol = nt * 16 + dcol;
        float s = sb[gcol];
        #pragma unroll
        for (int j = 0; j < 4; j++) {
            int grow = row0 + drow0 + j;
            if (grow < N_NODES) {
                comb[(size_t)grow * HID + gcol] = fmaxf(acc[nt][j], s);
            }
        }
    }
}

// ---------------- output GEMM: out = h @ W_out + b_out (fp32 vector) ----------------
__launch_bounds__(256)
__global__ void gemm_out(const float* __restrict__ h, const float* __restrict__ Wo,
                         const float* __restrict__ bo, float* __restrict__ out) {
    __shared__ float As[64][129];
    __shared__ float Ws[128][40];
    const int t = threadIdx.x;
    const int row0 = blockIdx.x * 64;

    #pragma unroll
    for (int i = 0; i < 8; i++) {
        int q = t + i * 256;
        int r = q >> 5, c4 = q & 31;
        int grow = row0 + r;
        float4 v = make_float4(0.f, 0.f, 0.f, 0.f);
        if (grow < N_NODES) v = *(const float4*)&h[(size_t)grow * HID + c4 * 4];
        As[r][c4 * 4 + 0] = v.x;
        As[r][c4 * 4 + 1] = v.y;
        As[r][c4 * 4 + 2] = v.z;
        As[r][c4 * 4 + 3] = v.w;
    }
    #pragma unroll
    for (int i = 0; i < 20; i++) {
        int idx = t + i * 256;
        Ws[idx / 40][idx % 40] = Wo[idx];
    }
    __syncthreads();

    const int r = t >> 2;
    const int c0 = t & 3;
    float acc[10] = {};
    #pragma unroll 4
    for (int k = 0; k < HID; k++) {
        float a = As[r][k];
        #pragma unroll
        for (int i = 0; i < 10; i++) {
            acc[i] = fmaf(a, Ws[k][c0 + 4 * i], acc[i]);
        }
    }
    int grow = row0 + r;
    if (grow < N_NODES) {
        #pragma unroll
        for (int i = 0; i < 10; i++) {
            out[(size_t)grow * C_OUT + c0 + 4 * i] = acc[i] + bo[c0 + 4 * i];
        }
    }
}

// ---------------- launch ----------------
extern "C" void kernel_launch(void* const* d_in, const int* in_sizes, int n_in,
                              void* d_out, int out_size, void* d_ws, size_t ws_size,
                              hipStream_t stream) {
    const float* x   = (const float*)d_in[0];
    const int*   ei  = (const int*)d_in[1];
    const float* Wi  = (const float*)d_in[2];
    const float* bi  = (const float*)d_in[3];
    const float* Wls = (const float*)d_in[4];
    const float* sbs = (const float*)d_in[5];
    const float* Wo  = (const float*)d_in[6];
    const float* bo  = (const float*)d_in[7];
    float* out = (float*)d_out;

    float* dinv    = (float*)d_ws;
    int*   indeg   = (int*)(dinv + 50176);
    int*   rowptr  = indeg + 50176;
    int*   cursor  = rowptr + 50304;
    int*   csr_src = cursor + 50176;
    unsigned short* Wth  = (unsigned short*)(csr_src + 800000);  // 128x512
    unsigned short* Wtl  = Wth + 65536;
    unsigned short* Wlth = Wtl + 65536;                          // 4x128x128
    unsigned short* Wltl = Wlth + 65536;
    float* x0 = (float*)(Wltl + 65536);
    float* hA = x0 + (size_t)N_NODES * HID;
    float* hB = hA + (size_t)N_NODES * HID;

    const int nodeBlocks = (N_NODES + 255) / 256;
    const int edgeBlocks = (E_EDGES + 255) / 256;
    const int gemmBlocks = (N_NODES + 63) / 64;
    const int aggBlocks  = (N_NODES + 3) / 4;

    zero_int<<<nodeBlocks, 256, 0, stream>>>(indeg, N_NODES);
    indeg_count<<<edgeBlocks, 256, 0, stream>>>(ei, indeg);
    dinv_k<<<nodeBlocks, 256, 0, stream>>>(indeg, dinv);
    scan_k<<<1, 1024, 0, stream>>>(indeg, rowptr, cursor);
    csr_fill<<<edgeBlocks, 256, 0, stream>>>(ei, cursor, csr_src);

    wprep_in<<<(F_IN * HID + 255) / 256, 256, 0, stream>>>(Wi, Wth, Wtl);
    wprep_layers<<<(N_LAYERS * HID * HID + 255) / 256, 256, 0, stream>>>(Wls, Wlth, Wltl);

    gemm_in_mfma<<<gemmBlocks, 256, 0, stream>>>(x, Wth, Wtl, bi, hA, x0);

    float* h    = hA;
    float* next = hB;
    for (int l = 0; l < N_LAYERS; l++) {
        aggregate<<<aggBlocks, 256, 0, stream>>>(rowptr, csr_src, dinv, h, x0, next);
        gemm_layer_mfma<<<gemmBlocks, 256, 0, stream>>>(Wlth + (size_t)l * HID * HID,
                                                        Wltl + (size_t)l * HID * HID,
                                                        sbs + (size_t)l * HID, next);
        float* tmp = h; h = next; next = tmp;
    }

    gemm_out<<<gemmBlocks, 256, 0, stream>>>(h, Wo, bo, out);
}

// Round 5
// 628.912 us; speedup vs baseline: 9.1735x; 1.2528x over previous
//
#include <hip/hip_runtime.h>

#define N_NODES 50000
#define E_EDGES 800000
#define F_IN 512
#define HID 128
#define N_LAYERS 4
#define C_OUT 40

typedef __attribute__((ext_vector_type(8))) short bf16x8;
typedef __attribute__((ext_vector_type(4))) float f32x4;

#define MFMA16(a, b, c) __builtin_amdgcn_mfma_f32_16x16x32_bf16(a, b, c, 0, 0, 0)

// split fp32 into bf16 hi (RNE) + bf16 lo (residual); a ~= hi + lo with ~2^-17 rel error
__device__ __forceinline__ void split2(float a, unsigned short& hi, unsigned short& lo) {
    unsigned u = __float_as_uint(a);
    unsigned r = u + 0x7FFFu + ((u >> 16) & 1u);
    hi = (unsigned short)(r >> 16);
    float hf = __uint_as_float(((unsigned)hi) << 16);
    lo = (unsigned short)(__float_as_uint(a - hf) >> 16);
}

// async global->LDS 16B DMA (LDS dest linear per-lane, source may be pre-swizzled)
__device__ __forceinline__ void async16(void* lds, const void* g) {
    __builtin_amdgcn_global_load_lds(
        (const __attribute__((address_space(1))) unsigned*)g,
        (__attribute__((address_space(3))) unsigned*)lds, 16, 0, 0);
}

// ---------------- degree / norm ----------------
__global__ void zero_int(int* p, int n) {
    int i = blockIdx.x * 256 + threadIdx.x;
    if (i < n) p[i] = 0;
}

__global__ void indeg_count(const int* __restrict__ ei, int* __restrict__ indeg) {
    int e = blockIdx.x * 256 + threadIdx.x;
    if (e < E_EDGES) {
        unsigned d = (unsigned)ei[E_EDGES + e];
        if (d < N_NODES) atomicAdd(&indeg[d], 1);
    }
}

__global__ void dinv_k(const int* __restrict__ indeg, float* __restrict__ dinv) {
    int i = blockIdx.x * 256 + threadIdx.x;
    if (i < N_NODES) dinv[i] = rsqrtf(1.0f + (float)indeg[i]);
}

// ---------------- single-block exclusive scan -> rowptr, cursor ----------------
__launch_bounds__(1024)
__global__ void scan_k(const int* __restrict__ indeg, int* __restrict__ rowptr,
                       int* __restrict__ cursor) {
    __shared__ int sums[1024];
    const int t = threadIdx.x;
    const int CH = 49;
    const int base = t * CH;
    int local = 0;
    for (int i = 0; i < CH; i++) {
        int idx = base + i;
        if (idx < N_NODES) local += indeg[idx];
    }
    sums[t] = local;
    __syncthreads();
    for (int off = 1; off < 1024; off <<= 1) {
        int v = sums[t];
        int add = (t >= off) ? sums[t - off] : 0;
        __syncthreads();
        sums[t] = v + add;
        __syncthreads();
    }
    int run = (t == 0) ? 0 : sums[t - 1];
    for (int i = 0; i < CH; i++) {
        int idx = base + i;
        if (idx < N_NODES) {
            rowptr[idx] = run;
            cursor[idx] = run;
            run += indeg[idx];
        }
    }
    if (t == 1023) rowptr[N_NODES] = sums[1023];
}

// ---------------- CSR fill ----------------
__global__ void csr_fill(const int* __restrict__ ei, int* __restrict__ cursor,
                         int* __restrict__ csr_src) {
    int e = blockIdx.x * 256 + threadIdx.x;
    if (e < E_EDGES) {
        unsigned s = (unsigned)ei[e];
        unsigned d = (unsigned)ei[E_EDGES + e];
        if (s < N_NODES && d < N_NODES) {
            int pos = atomicAdd(&cursor[d], 1);
            csr_src[pos] = (int)s;
        }
    }
}

// ---------------- weight prep: W[K][N] fp32 -> Wt_hi/Wt_lo [N][K] bf16 ----------------
__global__ void wprep_in(const float* __restrict__ W, unsigned short* __restrict__ Whi,
                         unsigned short* __restrict__ Wlo) {
    int idx = blockIdx.x * 256 + threadIdx.x;
    if (idx < F_IN * HID) {
        int k = idx >> 7, n = idx & 127;
        unsigned short hi, lo;
        split2(W[idx], hi, lo);
        Whi[(size_t)n * F_IN + k] = hi;
        Wlo[(size_t)n * F_IN + k] = lo;
    }
}

__global__ void wprep_layers(const float* __restrict__ W, unsigned short* __restrict__ Whi,
                             unsigned short* __restrict__ Wlo) {
    int idx = blockIdx.x * 256 + threadIdx.x;
    if (idx < N_LAYERS * HID * HID) {
        int l = idx >> 14;
        int rem = idx & 16383;
        int k = rem >> 7, n = rem & 127;
        unsigned short hi, lo;
        split2(W[idx], hi, lo);
        Whi[(size_t)l * HID * HID + n * HID + k] = hi;
        Wlo[(size_t)l * HID * HID + n * HID + k] = lo;
    }
}

// ---------------- input GEMM (MFMA split-bf16): h = relu(x @ W_in + b), x0 = h ----------------
// BM=64, BN=128(full), BK=64. 4 waves in 2x2 grid: wave (wr,wc) owns rows wr*32..+31,
// cols wc*64..+63. B staged to LDS via global_load_lds with pre-swizzled source.
__launch_bounds__(256)
__global__ void gemm_in_mfma(const float* __restrict__ x,
                             const unsigned short* __restrict__ Bth,
                             const unsigned short* __restrict__ Btl,
                             const float* __restrict__ bi,
                             float* __restrict__ h, float* __restrict__ x0) {
    __shared__ __align__(16) unsigned short Ah[64 * 64];    // 8 KB
    __shared__ __align__(16) unsigned short Al[64 * 64];    // 8 KB
    __shared__ __align__(16) unsigned short Bh[128 * 64];   // 16 KB
    __shared__ __align__(16) unsigned short Bl[128 * 64];   // 16 KB
    const int t = threadIdx.x;
    const int lane = t & 63;
    const int wv = t >> 6;
    const int wr = wv >> 1, wc = wv & 1;
    const int row0 = blockIdx.x * 64;
    const int fr = lane & 15;        // fragment row (A-row / B-col)
    const int fkg = lane >> 4;       // 16B k-granule 0..3

    f32x4 acc[2][4] = {};

    for (int k0 = 0; k0 < F_IN; k0 += 64) {
        // B tile DMA: [128n][64k] hi/lo; source address carries the XOR swizzle
        #pragma unroll
        for (int i = 0; i < 4; i++) {
            int g = t + i * 256;             // granule 0..1023
            int n = g >> 3, j = g & 7;
            int jp = j ^ (n & 7);
            size_t src = (size_t)n * F_IN + k0 + jp * 8;  // ushort index
            async16(&Bh[g * 8], &Bth[src]);
            async16(&Bl[g * 8], &Btl[src]);
        }
        // A tile: fp32 load -> split2 -> swizzled LDS write
        #pragma unroll
        for (int i = 0; i < 4; i++) {
            int q = t + i * 256;
            int r = q >> 4, c4 = q & 15;
            int grow = row0 + r;
            float4 v = make_float4(0.f, 0.f, 0.f, 0.f);
            if (grow < N_NODES) v = *(const float4*)&x[(size_t)grow * F_IN + k0 + c4 * 4];
            ushort4 uh, ul;
            split2(v.x, uh.x, ul.x); split2(v.y, uh.y, ul.y);
            split2(v.z, uh.z, ul.z); split2(v.w, uh.w, ul.w);
            int idx = (r * 64 + c4 * 4) ^ ((r & 7) << 3);
            *(ushort4*)&Ah[idx] = uh;
            *(ushort4*)&Al[idx] = ul;
        }
        __syncthreads();   // drains vmcnt (DMA) + lgkmcnt (ds_write)

        #pragma unroll
        for (int kk = 0; kk < 2; kk++) {
            bf16x8 ah[2], al[2];
            #pragma unroll
            for (int mt = 0; mt < 2; mt++) {
                int arow = wr * 32 + mt * 16 + fr;
                int aidx = (arow * 64 + kk * 32 + fkg * 8) ^ ((arow & 7) << 3);
                ah[mt] = *(bf16x8*)&Ah[aidx];
                al[mt] = *(bf16x8*)&Al[aidx];
            }
            #pragma unroll
            for (int nt = 0; nt < 4; nt++) {
                int n = wc * 64 + nt * 16 + fr;
                int bidx = (n * 64 + kk * 32 + fkg * 8) ^ ((n & 7) << 3);
                bf16x8 bh = *(bf16x8*)&Bh[bidx];
                bf16x8 bl = *(bf16x8*)&Bl[bidx];
                #pragma unroll
                for (int mt = 0; mt < 2; mt++) {
                    acc[mt][nt] = MFMA16(al[mt], bh, acc[mt][nt]);
                    acc[mt][nt] = MFMA16(ah[mt], bl, acc[mt][nt]);
                    acc[mt][nt] = MFMA16(ah[mt], bh, acc[mt][nt]);
                }
            }
        }
        __syncthreads();
    }

    // epilogue: C/D col = lane&15, row = (lane>>4)*4 + j
    const int dcol = lane & 15;
    const int dr0 = (lane >> 4) * 4;
    #pragma unroll
    for (int nt = 0; nt < 4; nt++) {
        int gcol = wc * 64 + nt * 16 + dcol;
        float b = bi[gcol];
        #pragma unroll
        for (int mt = 0; mt < 2; mt++) {
            #pragma unroll
            for (int j = 0; j < 4; j++) {
                int grow = row0 + wr * 32 + mt * 16 + dr0 + j;
                if (grow < N_NODES) {
                    float v = fmaxf(acc[mt][nt][j] + b, 0.f);
                    h[(size_t)grow * HID + gcol] = v;
                    x0[(size_t)grow * HID + gcol] = v;
                }
            }
        }
    }
}

// ---------------- aggregate (CSR gather) + residual combine ----------------
// Half-wave (32 lanes) per dst node; lane owns float4 of the 128-wide row.
__launch_bounds__(256)
__global__ void aggregate(const int* __restrict__ rowptr, const int* __restrict__ csr_src,
                          const float* __restrict__ dinv,
                          const float* __restrict__ h, const float* __restrict__ x0,
                          float* __restrict__ comb) {
    const int hw = threadIdx.x >> 5;
    const int lane = threadIdx.x & 31;
    const int node = blockIdx.x * 8 + hw;
    if (node >= N_NODES) return;

    const float4* h4 = (const float4*)h;
    const float4* x4 = (const float4*)x0;
    const float dd = dinv[node];
    const int beg = rowptr[node];
    const int end = rowptr[node + 1];

    float4 s0 = make_float4(0.f, 0.f, 0.f, 0.f);
    float4 s1 = make_float4(0.f, 0.f, 0.f, 0.f);
    int e = beg;
    for (; e + 2 <= end; e += 2) {
        int sa = csr_src[e];
        int sb = csr_src[e + 1];
        float wa = dinv[sa];
        float wb = dinv[sb];
        float4 va = h4[(size_t)sa * 32 + lane];
        float4 vb = h4[(size_t)sb * 32 + lane];
        s0.x = fmaf(wa, va.x, s0.x); s0.y = fmaf(wa, va.y, s0.y);
        s0.z = fmaf(wa, va.z, s0.z); s0.w = fmaf(wa, va.w, s0.w);
        s1.x = fmaf(wb, vb.x, s1.x); s1.y = fmaf(wb, vb.y, s1.y);
        s1.z = fmaf(wb, vb.z, s1.z); s1.w = fmaf(wb, vb.w, s1.w);
    }
    if (e < end) {
        int sa = csr_src[e];
        float wa = dinv[sa];
        float4 va = h4[(size_t)sa * 32 + lane];
        s0.x = fmaf(wa, va.x, s0.x); s0.y = fmaf(wa, va.y, s0.y);
        s0.z = fmaf(wa, va.z, s0.z); s0.w = fmaf(wa, va.w, s0.w);
    }
    float4 sum = make_float4(s0.x + s1.x, s0.y + s1.y, s0.z + s1.z, s0.w + s1.w);

    float4 hv = h4[(size_t)node * 32 + lane];
    float4 xv = x4[(size_t)node * 32 + lane];
    const float a = 0.8f * dd;
    float4 o;
    o.x = a * fmaf(dd, hv.x, sum.x) + 0.1f * hv.x + 0.1f * xv.x;
    o.y = a * fmaf(dd, hv.y, sum.y) + 0.1f * hv.y + 0.1f * xv.y;
    o.z = a * fmaf(dd, hv.z, sum.z) + 0.1f * hv.z + 0.1f * xv.z;
    o.w = a * fmaf(dd, hv.w, sum.w) + 0.1f * hv.w + 0.1f * xv.w;
    ((float4*)comb)[(size_t)node * 32 + lane] = o;
}

// ---------------- layer GEMM (MFMA split-bf16, in place): comb <- SReLU(comb @ W) ----------------
// A (64x128, full K) staged once; B staged in two 64-k halves. LDS = 64 KB -> 2 blocks/CU.
__launch_bounds__(256)
__global__ void gemm_layer_mfma(const unsigned short* __restrict__ Bth,
                                const unsigned short* __restrict__ Btl,
                                const float* __restrict__ sb,
                                float* __restrict__ comb) {
    __shared__ __align__(16) unsigned short Ah[64 * 128];   // 16 KB
    __shared__ __align__(16) unsigned short Al[64 * 128];   // 16 KB
    __shared__ __align__(16) unsigned short Bh[128 * 64];   // 16 KB
    __shared__ __align__(16) unsigned short Bl[128 * 64];   // 16 KB
    const int t = threadIdx.x;
    const int lane = t & 63;
    const int wv = t >> 6;
    const int wr = wv >> 1, wc = wv & 1;
    const int row0 = blockIdx.x * 64;
    const int fr = lane & 15;
    const int fkg = lane >> 4;

    f32x4 acc[2][4] = {};

    // B half-tile DMA issue (khalf in ushort units)
    auto stageB = [&](int khalf) {
        #pragma unroll
        for (int i = 0; i < 4; i++) {
            int g = t + i * 256;             // granule 0..1023
            int n = g >> 3, j = g & 7;
            int jp = j ^ (n & 7);
            size_t src = (size_t)n * HID + khalf + jp * 8;
            async16(&Bh[g * 8], &Bth[src]);
            async16(&Bl[g * 8], &Btl[src]);
        }
    };

    stageB(0);
    // A stage: full 64x128, fp32 -> split -> swizzled LDS
    #pragma unroll
    for (int i = 0; i < 8; i++) {
        int q = t + i * 256;
        int r = q >> 5, c4 = q & 31;
        int grow = row0 + r;
        float4 v = make_float4(0.f, 0.f, 0.f, 0.f);
        if (grow < N_NODES) v = *(const float4*)&comb[(size_t)grow * HID + c4 * 4];
        ushort4 uh, ul;
        split2(v.x, uh.x, ul.x); split2(v.y, uh.y, ul.y);
        split2(v.z, uh.z, ul.z); split2(v.w, uh.w, ul.w);
        int idx = (r * 128 + c4 * 4) ^ ((r & 7) << 3);
        *(ushort4*)&Ah[idx] = uh;
        *(ushort4*)&Al[idx] = ul;
    }
    __syncthreads();

    #pragma unroll
    for (int half = 0; half < 2; half++) {
        #pragma unroll
        for (int kk2 = 0; kk2 < 2; kk2++) {
            int kk = half * 2 + kk2;
            bf16x8 ah[2], al[2];
            #pragma unroll
            for (int mt = 0; mt < 2; mt++) {
                int arow = wr * 32 + mt * 16 + fr;
                int aidx = (arow * 128 + kk * 32 + fkg * 8) ^ ((arow & 7) << 3);
                ah[mt] = *(bf16x8*)&Ah[aidx];
                al[mt] = *(bf16x8*)&Al[aidx];
            }
            #pragma unroll
            for (int nt = 0; nt < 4; nt++) {
                int n = wc * 64 + nt * 16 + fr;
                int bidx = (n * 64 + kk2 * 32 + fkg * 8) ^ ((n & 7) << 3);
                bf16x8 bh = *(bf16x8*)&Bh[bidx];
                bf16x8 bl = *(bf16x8*)&Bl[bidx];
                #pragma unroll
                for (int mt = 0; mt < 2; mt++) {
                    acc[mt][nt] = MFMA16(al[mt], bh, acc[mt][nt]);
                    acc[mt][nt] = MFMA16(ah[mt], bl, acc[mt][nt]);
                    acc[mt][nt] = MFMA16(ah[mt], bh, acc[mt][nt]);
                }
            }
        }
        if (half == 0) {
            __syncthreads();      // all waves done reading B half0
            stageB(64);
            __syncthreads();      // B half1 resident
        }
    }

    // SReLU epilogue, in place (all reads were staged before any write)
    const int dcol = lane & 15;
    const int dr0 = (lane >> 4) * 4;
    #pragma unroll
    for (int nt = 0; nt < 4; nt++) {
        int gcol = wc * 64 + nt * 16 + dcol;
        float s = sb[gcol];
        #pragma unroll
        for (int mt = 0; mt < 2; mt++) {
            #pragma unroll
            for (int j = 0; j < 4; j++) {
                int grow = row0 + wr * 32 + mt * 16 + dr0 + j;
                if (grow < N_NODES) {
                    comb[(size_t)grow * HID + gcol] = fmaxf(acc[mt][nt][j], s);
                }
            }
        }
    }
}

// ---------------- output GEMM: out = h @ W_out + b_out (fp32 vector) ----------------
__launch_bounds__(256)
__global__ void gemm_out(const float* __restrict__ h, const float* __restrict__ Wo,
                         const float* __restrict__ bo, float* __restrict__ out) {
    __shared__ float As[64][129];
    __shared__ float Ws[128][40];
    const int t = threadIdx.x;
    const int row0 = blockIdx.x * 64;

    #pragma unroll
    for (int i = 0; i < 8; i++) {
        int q = t + i * 256;
        int r = q >> 5, c4 = q & 31;
        int grow = row0 + r;
        float4 v = make_float4(0.f, 0.f, 0.f, 0.f);
        if (grow < N_NODES) v = *(const float4*)&h[(size_t)grow * HID + c4 * 4];
        As[r][c4 * 4 + 0] = v.x;
        As[r][c4 * 4 + 1] = v.y;
        As[r][c4 * 4 + 2] = v.z;
        As[r][c4 * 4 + 3] = v.w;
    }
    #pragma unroll
    for (int i = 0; i < 20; i++) {
        int idx = t + i * 256;
        Ws[idx / 40][idx % 40] = Wo[idx];
    }
    __syncthreads();

    const int r = t >> 2;
    const int c0 = t & 3;
    float acc[10] = {};
    #pragma unroll 4
    for (int k = 0; k < HID; k++) {
        float a = As[r][k];
        #pragma unroll
        for (int i = 0; i < 10; i++) {
            acc[i] = fmaf(a, Ws[k][c0 + 4 * i], acc[i]);
        }
    }
    int grow = row0 + r;
    if (grow < N_NODES) {
        #pragma unroll
        for (int i = 0; i < 10; i++) {
            out[(size_t)grow * C_OUT + c0 + 4 * i] = acc[i] + bo[c0 + 4 * i];
        }
    }
}

// ---------------- launch ----------------
extern "C" void kernel_launch(void* const* d_in, const int* in_sizes, int n_in,
                              void* d_out, int out_size, void* d_ws, size_t ws_size,
                              hipStream_t stream) {
    const float* x   = (const float*)d_in[0];
    const int*   ei  = (const int*)d_in[1];
    const float* Wi  = (const float*)d_in[2];
    const float* bi  = (const float*)d_in[3];
    const float* Wls = (const float*)d_in[4];
    const float* sbs = (const float*)d_in[5];
    const float* Wo  = (const float*)d_in[6];
    const float* bo  = (const float*)d_in[7];
    float* out = (float*)d_out;

    float* dinv    = (float*)d_ws;
    int*   indeg   = (int*)(dinv + 50176);
    int*   rowptr  = indeg + 50176;
    int*   cursor  = rowptr + 50304;
    int*   csr_src = cursor + 50176;
    unsigned short* Wth  = (unsigned short*)(csr_src + 800000);  // [128][512]
    unsigned short* Wtl  = Wth + 65536;
    unsigned short* Wlth = Wtl + 65536;                          // [4][128][128]
    unsigned short* Wltl = Wlth + 65536;
    float* x0 = (float*)(Wltl + 65536);
    float* hA = x0 + (size_t)N_NODES * HID;
    float* hB = hA + (size_t)N_NODES * HID;

    const int nodeBlocks = (N_NODES + 255) / 256;
    const int edgeBlocks = (E_EDGES + 255) / 256;
    const int gemmBlocks = (N_NODES + 63) / 64;
    const int aggBlocks  = (N_NODES + 7) / 8;

    zero_int<<<nodeBlocks, 256, 0, stream>>>(indeg, N_NODES);
    indeg_count<<<edgeBlocks, 256, 0, stream>>>(ei, indeg);
    dinv_k<<<nodeBlocks, 256, 0, stream>>>(indeg, dinv);
    scan_k<<<1, 1024, 0, stream>>>(indeg, rowptr, cursor);
    csr_fill<<<edgeBlocks, 256, 0, stream>>>(ei, cursor, csr_src);

    wprep_in<<<(F_IN * HID + 255) / 256, 256, 0, stream>>>(Wi, Wth, Wtl);
    wprep_layers<<<(N_LAYERS * HID * HID + 255) / 256, 256, 0, stream>>>(Wls, Wlth, Wltl);

    gemm_in_mfma<<<gemmBlocks, 256, 0, stream>>>(x, Wth, Wtl, bi, hA, x0);

    float* h    = hA;
    float* next = hB;
    for (int l = 0; l < N_LAYERS; l++) {
        aggregate<<<aggBlocks, 256, 0, stream>>>(rowptr, csr_src, dinv, h, x0, next);
        gemm_layer_mfma<<<gemmBlocks, 256, 0, stream>>>(Wlth + (size_t)l * HID * HID,
                                                        Wltl + (size_t)l * HID * HID,
                                                        sbs + (size_t)l * HID, next);
        float* tmp = h; h = next; next = tmp;
    }

    gemm_out<<<gemmBlocks, 256, 0, stream>>>(h, Wo, bo, out);
}

// Round 6
// 503.594 us; speedup vs baseline: 11.4563x; 1.2488x over previous
//
#include <hip/hip_runtime.h>

#define N_NODES 50000
#define E_EDGES 800000
#define F_IN 512
#define HID 128
#define N_LAYERS 4
#define C_OUT 40
#define SCAN_BLOCKS 196   // ceil(50000/256)

typedef __attribute__((ext_vector_type(8))) short bf16x8;
typedef __attribute__((ext_vector_type(4))) float f32x4;

#define MFMA16(a, b, c) __builtin_amdgcn_mfma_f32_16x16x32_bf16(a, b, c, 0, 0, 0)

// split fp32 into bf16 hi (RNE) + bf16 lo (residual); a ~= hi + lo with ~2^-17 rel error
__device__ __forceinline__ void split2(float a, unsigned short& hi, unsigned short& lo) {
    unsigned u = __float_as_uint(a);
    unsigned r = u + 0x7FFFu + ((u >> 16) & 1u);
    hi = (unsigned short)(r >> 16);
    float hf = __uint_as_float(((unsigned)hi) << 16);
    lo = (unsigned short)(__float_as_uint(a - hf) >> 16);
}

// async global->LDS 16B DMA
__device__ __forceinline__ void async16(void* lds, const void* g) {
    __builtin_amdgcn_global_load_lds(
        (const __attribute__((address_space(1))) unsigned*)g,
        (__attribute__((address_space(3))) unsigned*)lds, 16, 0, 0);
}

// ---------------- degree / norm ----------------
__global__ void zero_int(int* p, int n) {
    int i = blockIdx.x * 256 + threadIdx.x;
    if (i < n) p[i] = 0;
}

__global__ void indeg_count(const int* __restrict__ ei, int* __restrict__ indeg) {
    int e = blockIdx.x * 256 + threadIdx.x;
    if (e < E_EDGES) {
        unsigned d = (unsigned)ei[E_EDGES + e];
        if (d < N_NODES) atomicAdd(&indeg[d], 1);
    }
}

__global__ void dinv_k(const int* __restrict__ indeg, float* __restrict__ dinv) {
    int i = blockIdx.x * 256 + threadIdx.x;
    if (i < N_NODES) dinv[i] = rsqrtf(1.0f + (float)indeg[i]);
}

// ---------------- 3-phase parallel exclusive scan ----------------
// p1: per-block sums
__global__ void scan_p1(const int* __restrict__ indeg, int* __restrict__ bsum) {
    __shared__ int red[4];
    int i = blockIdx.x * 256 + threadIdx.x;
    int v = (i < N_NODES) ? indeg[i] : 0;
    // wave reduce (64 lanes)
    #pragma unroll
    for (int off = 32; off > 0; off >>= 1) v += __shfl_down(v, off, 64);
    if ((threadIdx.x & 63) == 0) red[threadIdx.x >> 6] = v;
    __syncthreads();
    if (threadIdx.x == 0) bsum[blockIdx.x] = red[0] + red[1] + red[2] + red[3];
}

// p2: single block scans SCAN_BLOCKS partials -> exclusive boff, total -> rowptr[N]
__launch_bounds__(256)
__global__ void scan_p2(const int* __restrict__ bsum, int* __restrict__ boff,
                        int* __restrict__ rowptr) {
    __shared__ int s[256];
    int t = threadIdx.x;
    int v = (t < SCAN_BLOCKS) ? bsum[t] : 0;
    s[t] = v;
    __syncthreads();
    #pragma unroll
    for (int off = 1; off < 256; off <<= 1) {
        int a = s[t];
        int b = (t >= off) ? s[t - off] : 0;
        __syncthreads();
        s[t] = a + b;
        __syncthreads();
    }
    if (t < SCAN_BLOCKS) boff[t] = (t == 0) ? 0 : s[t - 1];
    if (t == 255) rowptr[N_NODES] = s[SCAN_BLOCKS - 1];
}

// p3: in-block exclusive scan + block offset -> rowptr, cursor
__launch_bounds__(256)
__global__ void scan_p3(const int* __restrict__ indeg, const int* __restrict__ boff,
                        int* __restrict__ rowptr, int* __restrict__ cursor) {
    __shared__ int s[256];
    int t = threadIdx.x;
    int i = blockIdx.x * 256 + t;
    int v = (i < N_NODES) ? indeg[i] : 0;
    s[t] = v;
    __syncthreads();
    #pragma unroll
    for (int off = 1; off < 256; off <<= 1) {
        int a = s[t];
        int b = (t >= off) ? s[t - off] : 0;
        __syncthreads();
        s[t] = a + b;
        __syncthreads();
    }
    if (i < N_NODES) {
        int excl = boff[blockIdx.x] + s[t] - v;   // inclusive - self = exclusive
        rowptr[i] = excl;
        cursor[i] = excl;
    }
}

// ---------------- CSR fill ----------------
__global__ void csr_fill(const int* __restrict__ ei, int* __restrict__ cursor,
                         int* __restrict__ csr_src) {
    int e = blockIdx.x * 256 + threadIdx.x;
    if (e < E_EDGES) {
        unsigned s = (unsigned)ei[e];
        unsigned d = (unsigned)ei[E_EDGES + e];
        if (s < N_NODES && d < N_NODES) {
            int pos = atomicAdd(&cursor[d], 1);
            csr_src[pos] = (int)s;
        }
    }
}

// ---------------- weight prep: W[K][N] fp32 -> Wt_hi/Wt_lo [N][K] bf16 ----------------
__global__ void wprep_in(const float* __restrict__ W, unsigned short* __restrict__ Whi,
                         unsigned short* __restrict__ Wlo) {
    int idx = blockIdx.x * 256 + threadIdx.x;
    if (idx < F_IN * HID) {
        int k = idx >> 7, n = idx & 127;
        unsigned short hi, lo;
        split2(W[idx], hi, lo);
        Whi[(size_t)n * F_IN + k] = hi;
        Wlo[(size_t)n * F_IN + k] = lo;
    }
}

__global__ void wprep_layers(const float* __restrict__ W, unsigned short* __restrict__ Whi,
                             unsigned short* __restrict__ Wlo) {
    int idx = blockIdx.x * 256 + threadIdx.x;
    if (idx < N_LAYERS * HID * HID) {
        int l = idx >> 14;
        int rem = idx & 16383;
        int k = rem >> 7, n = rem & 127;
        unsigned short hi, lo;
        split2(W[idx], hi, lo);
        Whi[(size_t)l * HID * HID + n * HID + k] = hi;
        Wlo[(size_t)l * HID * HID + n * HID + k] = lo;
    }
}

// ---------------- input GEMM (MFMA split-bf16): h = relu(x @ W_in + b), x0 = h ----------------
__launch_bounds__(256)
__global__ void gemm_in_mfma(const float* __restrict__ x,
                             const unsigned short* __restrict__ Bth,
                             const unsigned short* __restrict__ Btl,
                             const float* __restrict__ bi,
                             float* __restrict__ h, float* __restrict__ x0) {
    __shared__ __align__(16) unsigned short Ah[64 * 64];
    __shared__ __align__(16) unsigned short Al[64 * 64];
    __shared__ __align__(16) unsigned short Bh[128 * 64];
    __shared__ __align__(16) unsigned short Bl[128 * 64];
    const int t = threadIdx.x;
    const int lane = t & 63;
    const int wv = t >> 6;
    const int wr = wv >> 1, wc = wv & 1;
    const int row0 = blockIdx.x * 64;
    const int fr = lane & 15;
    const int fkg = lane >> 4;

    f32x4 acc[2][4] = {};

    for (int k0 = 0; k0 < F_IN; k0 += 64) {
        #pragma unroll
        for (int i = 0; i < 4; i++) {
            int g = t + i * 256;
            int n = g >> 3, j = g & 7;
            int jp = j ^ (n & 7);
            size_t src = (size_t)n * F_IN + k0 + jp * 8;
            async16(&Bh[g * 8], &Bth[src]);
            async16(&Bl[g * 8], &Btl[src]);
        }
        #pragma unroll
        for (int i = 0; i < 4; i++) {
            int q = t + i * 256;
            int r = q >> 4, c4 = q & 15;
            int grow = row0 + r;
            float4 v = make_float4(0.f, 0.f, 0.f, 0.f);
            if (grow < N_NODES) v = *(const float4*)&x[(size_t)grow * F_IN + k0 + c4 * 4];
            ushort4 uh, ul;
            split2(v.x, uh.x, ul.x); split2(v.y, uh.y, ul.y);
            split2(v.z, uh.z, ul.z); split2(v.w, uh.w, ul.w);
            int idx = (r * 64 + c4 * 4) ^ ((r & 7) << 3);
            *(ushort4*)&Ah[idx] = uh;
            *(ushort4*)&Al[idx] = ul;
        }
        __syncthreads();

        #pragma unroll
        for (int kk = 0; kk < 2; kk++) {
            bf16x8 ah[2], al[2];
            #pragma unroll
            for (int mt = 0; mt < 2; mt++) {
                int arow = wr * 32 + mt * 16 + fr;
                int aidx = (arow * 64 + kk * 32 + fkg * 8) ^ ((arow & 7) << 3);
                ah[mt] = *(bf16x8*)&Ah[aidx];
                al[mt] = *(bf16x8*)&Al[aidx];
            }
            #pragma unroll
            for (int nt = 0; nt < 4; nt++) {
                int n = wc * 64 + nt * 16 + fr;
                int bidx = (n * 64 + kk * 32 + fkg * 8) ^ ((n & 7) << 3);
                bf16x8 bh = *(bf16x8*)&Bh[bidx];
                bf16x8 bl = *(bf16x8*)&Bl[bidx];
                #pragma unroll
                for (int mt = 0; mt < 2; mt++) {
                    acc[mt][nt] = MFMA16(al[mt], bh, acc[mt][nt]);
                    acc[mt][nt] = MFMA16(ah[mt], bl, acc[mt][nt]);
                    acc[mt][nt] = MFMA16(ah[mt], bh, acc[mt][nt]);
                }
            }
        }
        __syncthreads();
    }

    const int dcol = lane & 15;
    const int dr0 = (lane >> 4) * 4;
    #pragma unroll
    for (int nt = 0; nt < 4; nt++) {
        int gcol = wc * 64 + nt * 16 + dcol;
        float b = bi[gcol];
        #pragma unroll
        for (int mt = 0; mt < 2; mt++) {
            #pragma unroll
            for (int j = 0; j < 4; j++) {
                int grow = row0 + wr * 32 + mt * 16 + dr0 + j;
                if (grow < N_NODES) {
                    float v = fmaxf(acc[mt][nt][j] + b, 0.f);
                    h[(size_t)grow * HID + gcol] = v;
                    x0[(size_t)grow * HID + gcol] = v;
                }
            }
        }
    }
}

// ---------------- aggregate (CSR gather) + residual combine ----------------
// Half-wave (32 lanes) per dst node; lane owns float4; 4x unrolled edge loop.
__launch_bounds__(256)
__global__ void aggregate(const int* __restrict__ rowptr, const int* __restrict__ csr_src,
                          const float* __restrict__ dinv,
                          const float* __restrict__ h, const float* __restrict__ x0,
                          float* __restrict__ comb) {
    const int hw = threadIdx.x >> 5;
    const int lane = threadIdx.x & 31;
    const int node = blockIdx.x * 8 + hw;
    if (node >= N_NODES) return;

    const float4* h4 = (const float4*)h;
    const float4* x4 = (const float4*)x0;
    const float dd = dinv[node];
    const int beg = rowptr[node];
    const int end = rowptr[node + 1];

    float4 s0 = make_float4(0.f, 0.f, 0.f, 0.f);
    float4 s1 = make_float4(0.f, 0.f, 0.f, 0.f);
    float4 s2 = make_float4(0.f, 0.f, 0.f, 0.f);
    float4 s3 = make_float4(0.f, 0.f, 0.f, 0.f);
    int e = beg;
    for (; e + 4 <= end; e += 4) {
        int sa = csr_src[e + 0];
        int sb = csr_src[e + 1];
        int sc = csr_src[e + 2];
        int sd = csr_src[e + 3];
        float wa = dinv[sa], wb = dinv[sb], wc = dinv[sc], wd = dinv[sd];
        float4 va = h4[(size_t)sa * 32 + lane];
        float4 vb = h4[(size_t)sb * 32 + lane];
        float4 vc = h4[(size_t)sc * 32 + lane];
        float4 vd = h4[(size_t)sd * 32 + lane];
        s0.x = fmaf(wa, va.x, s0.x); s0.y = fmaf(wa, va.y, s0.y);
        s0.z = fmaf(wa, va.z, s0.z); s0.w = fmaf(wa, va.w, s0.w);
        s1.x = fmaf(wb, vb.x, s1.x); s1.y = fmaf(wb, vb.y, s1.y);
        s1.z = fmaf(wb, vb.z, s1.z); s1.w = fmaf(wb, vb.w, s1.w);
        s2.x = fmaf(wc, vc.x, s2.x); s2.y = fmaf(wc, vc.y, s2.y);
        s2.z = fmaf(wc, vc.z, s2.z); s2.w = fmaf(wc, vc.w, s2.w);
        s3.x = fmaf(wd, vd.x, s3.x); s3.y = fmaf(wd, vd.y, s3.y);
        s3.z = fmaf(wd, vd.z, s3.z); s3.w = fmaf(wd, vd.w, s3.w);
    }
    for (; e < end; e++) {
        int sa = csr_src[e];
        float wa = dinv[sa];
        float4 va = h4[(size_t)sa * 32 + lane];
        s0.x = fmaf(wa, va.x, s0.x); s0.y = fmaf(wa, va.y, s0.y);
        s0.z = fmaf(wa, va.z, s0.z); s0.w = fmaf(wa, va.w, s0.w);
    }
    float4 sum;
    sum.x = (s0.x + s1.x) + (s2.x + s3.x);
    sum.y = (s0.y + s1.y) + (s2.y + s3.y);
    sum.z = (s0.z + s1.z) + (s2.z + s3.z);
    sum.w = (s0.w + s1.w) + (s2.w + s3.w);

    float4 hv = h4[(size_t)node * 32 + lane];
    float4 xv = x4[(size_t)node * 32 + lane];
    const float a = 0.8f * dd;
    float4 o;
    o.x = a * fmaf(dd, hv.x, sum.x) + 0.1f * hv.x + 0.1f * xv.x;
    o.y = a * fmaf(dd, hv.y, sum.y) + 0.1f * hv.y + 0.1f * xv.y;
    o.z = a * fmaf(dd, hv.z, sum.z) + 0.1f * hv.z + 0.1f * xv.z;
    o.w = a * fmaf(dd, hv.w, sum.w) + 0.1f * hv.w + 0.1f * xv.w;
    ((float4*)comb)[(size_t)node * 32 + lane] = o;
}

// ---------------- layer GEMM (MFMA split-bf16, in place): comb <- SReLU(comb @ W) ----------------
__launch_bounds__(256)
__global__ void gemm_layer_mfma(const unsigned short* __restrict__ Bth,
                                const unsigned short* __restrict__ Btl,
                                const float* __restrict__ sb,
                                float* __restrict__ comb) {
    __shared__ __align__(16) unsigned short Ah[64 * 128];
    __shared__ __align__(16) unsigned short Al[64 * 128];
    __shared__ __align__(16) unsigned short Bh[128 * 64];
    __shared__ __align__(16) unsigned short Bl[128 * 64];
    const int t = threadIdx.x;
    const int lane = t & 63;
    const int wv = t >> 6;
    const int wr = wv >> 1, wc = wv & 1;
    const int row0 = blockIdx.x * 64;
    const int fr = lane & 15;
    const int fkg = lane >> 4;

    f32x4 acc[2][4] = {};

    auto stageB = [&](int khalf) {
        #pragma unroll
        for (int i = 0; i < 4; i++) {
            int g = t + i * 256;
            int n = g >> 3, j = g & 7;
            int jp = j ^ (n & 7);
            size_t src = (size_t)n * HID + khalf + jp * 8;
            async16(&Bh[g * 8], &Bth[src]);
            async16(&Bl[g * 8], &Btl[src]);
        }
    };

    stageB(0);
    #pragma unroll
    for (int i = 0; i < 8; i++) {
        int q = t + i * 256;
        int r = q >> 5, c4 = q & 31;
        int grow = row0 + r;
        float4 v = make_float4(0.f, 0.f, 0.f, 0.f);
        if (grow < N_NODES) v = *(const float4*)&comb[(size_t)grow * HID + c4 * 4];
        ushort4 uh, ul;
        split2(v.x, uh.x, ul.x); split2(v.y, uh.y, ul.y);
        split2(v.z, uh.z, ul.z); split2(v.w, uh.w, ul.w);
        int idx = (r * 128 + c4 * 4) ^ ((r & 7) << 3);
        *(ushort4*)&Ah[idx] = uh;
        *(ushort4*)&Al[idx] = ul;
    }
    __syncthreads();

    #pragma unroll
    for (int half = 0; half < 2; half++) {
        #pragma unroll
        for (int kk2 = 0; kk2 < 2; kk2++) {
            int kk = half * 2 + kk2;
            bf16x8 ah[2], al[2];
            #pragma unroll
            for (int mt = 0; mt < 2; mt++) {
                int arow = wr * 32 + mt * 16 + fr;
                int aidx = (arow * 128 + kk * 32 + fkg * 8) ^ ((arow & 7) << 3);
                ah[mt] = *(bf16x8*)&Ah[aidx];
                al[mt] = *(bf16x8*)&Al[aidx];
            }
            #pragma unroll
            for (int nt = 0; nt < 4; nt++) {
                int n = wc * 64 + nt * 16 + fr;
                int bidx = (n * 64 + kk2 * 32 + fkg * 8) ^ ((n & 7) << 3);
                bf16x8 bh = *(bf16x8*)&Bh[bidx];
                bf16x8 bl = *(bf16x8*)&Bl[bidx];
                #pragma unroll
                for (int mt = 0; mt < 2; mt++) {
                    acc[mt][nt] = MFMA16(al[mt], bh, acc[mt][nt]);
                    acc[mt][nt] = MFMA16(ah[mt], bl, acc[mt][nt]);
                    acc[mt][nt] = MFMA16(ah[mt], bh, acc[mt][nt]);
                }
            }
        }
        if (half == 0) {
            __syncthreads();
            stageB(64);
            __syncthreads();
        }
    }

    const int dcol = lane & 15;
    const int dr0 = (lane >> 4) * 4;
    #pragma unroll
    for (int nt = 0; nt < 4; nt++) {
        int gcol = wc * 64 + nt * 16 + dcol;
        float s = sb[gcol];
        #pragma unroll
        for (int mt = 0; mt < 2; mt++) {
            #pragma unroll
            for (int j = 0; j < 4; j++) {
                int grow = row0 + wr * 32 + mt * 16 + dr0 + j;
                if (grow < N_NODES) {
                    comb[(size_t)grow * HID + gcol] = fmaxf(acc[mt][nt][j], s);
                }
            }
        }
    }
}

// ---------------- output GEMM: out = h @ W_out + b_out (fp32 vector) ----------------
__launch_bounds__(256)
__global__ void gemm_out(const float* __restrict__ h, const float* __restrict__ Wo,
                         const float* __restrict__ bo, float* __restrict__ out) {
    __shared__ float As[64][129];
    __shared__ float Ws[128][40];
    const int t = threadIdx.x;
    const int row0 = blockIdx.x * 64;

    #pragma unroll
    for (int i = 0; i < 8; i++) {
        int q = t + i * 256;
        int r = q >> 5, c4 = q & 31;
        int grow = row0 + r;
        float4 v = make_float4(0.f, 0.f, 0.f, 0.f);
        if (grow < N_NODES) v = *(const float4*)&h[(size_t)grow * HID + c4 * 4];
        As[r][c4 * 4 + 0] = v.x;
        As[r][c4 * 4 + 1] = v.y;
        As[r][c4 * 4 + 2] = v.z;
        As[r][c4 * 4 + 3] = v.w;
    }
    #pragma unroll
    for (int i = 0; i < 20; i++) {
        int idx = t + i * 256;
        Ws[idx / 40][idx % 40] = Wo[idx];
    }
    __syncthreads();

    const int r = t >> 2;
    const int c0 = t & 3;
    float acc[10] = {};
    #pragma unroll 4
    for (int k = 0; k < HID; k++) {
        float a = As[r][k];
        #pragma unroll
        for (int i = 0; i < 10; i++) {
            acc[i] = fmaf(a, Ws[k][c0 + 4 * i], acc[i]);
        }
    }
    int grow = row0 + r;
    if (grow < N_NODES) {
        #pragma unroll
        for (int i = 0; i < 10; i++) {
            out[(size_t)grow * C_OUT + c0 + 4 * i] = acc[i] + bo[c0 + 4 * i];
        }
    }
}

// ---------------- launch ----------------
extern "C" void kernel_launch(void* const* d_in, const int* in_sizes, int n_in,
                              void* d_out, int out_size, void* d_ws, size_t ws_size,
                              hipStream_t stream) {
    const float* x   = (const float*)d_in[0];
    const int*   ei  = (const int*)d_in[1];
    const float* Wi  = (const float*)d_in[2];
    const float* bi  = (const float*)d_in[3];
    const float* Wls = (const float*)d_in[4];
    const float* sbs = (const float*)d_in[5];
    const float* Wo  = (const float*)d_in[6];
    const float* bo  = (const float*)d_in[7];
    float* out = (float*)d_out;

    float* dinv    = (float*)d_ws;
    int*   indeg   = (int*)(dinv + 50176);
    int*   rowptr  = indeg + 50176;
    int*   cursor  = rowptr + 50304;
    int*   bsum    = cursor + 50176;                // 256 i
    int*   boff    = bsum + 256;                    // 256 i
    int*   csr_src = boff + 256;                    // 800000 i
    unsigned short* Wth  = (unsigned short*)(csr_src + 800000);
    unsigned short* Wtl  = Wth + 65536;
    unsigned short* Wlth = Wtl + 65536;
    unsigned short* Wltl = Wlth + 65536;
    float* x0 = (float*)(Wltl + 65536);
    float* hA = x0 + (size_t)N_NODES * HID;
    float* hB = hA + (size_t)N_NODES * HID;

    const int nodeBlocks = (N_NODES + 255) / 256;   // 196
    const int edgeBlocks = (E_EDGES + 255) / 256;
    const int gemmBlocks = (N_NODES + 63) / 64;
    const int aggBlocks  = (N_NODES + 7) / 8;

    zero_int<<<nodeBlocks, 256, 0, stream>>>(indeg, N_NODES);
    indeg_count<<<edgeBlocks, 256, 0, stream>>>(ei, indeg);
    dinv_k<<<nodeBlocks, 256, 0, stream>>>(indeg, dinv);
    scan_p1<<<SCAN_BLOCKS, 256, 0, stream>>>(indeg, bsum);
    scan_p2<<<1, 256, 0, stream>>>(bsum, boff, rowptr);
    scan_p3<<<SCAN_BLOCKS, 256, 0, stream>>>(indeg, boff, rowptr, cursor);
    csr_fill<<<edgeBlocks, 256, 0, stream>>>(ei, cursor, csr_src);

    wprep_in<<<(F_IN * HID + 255) / 256, 256, 0, stream>>>(Wi, Wth, Wtl);
    wprep_layers<<<(N_LAYERS * HID * HID + 255) / 256, 256, 0, stream>>>(Wls, Wlth, Wltl);

    gemm_in_mfma<<<gemmBlocks, 256, 0, stream>>>(x, Wth, Wtl, bi, hA, x0);

    float* h    = hA;
    float* next = hB;
    for (int l = 0; l < N_LAYERS; l++) {
        aggregate<<<aggBlocks, 256, 0, stream>>>(rowptr, csr_src, dinv, h, x0, next);
        gemm_layer_mfma<<<gemmBlocks, 256, 0, stream>>>(Wlth + (size_t)l * HID * HID,
                                                        Wltl + (size_t)l * HID * HID,
                                                        sbs + (size_t)l * HID, next);
        float* tmp = h; h = next; next = tmp;
    }

    gemm_out<<<gemmBlocks, 256, 0, stream>>>(h, Wo, bo, out);
}